// Round 5
// baseline (37.538 us; speedup 1.0000x reference)
//
#include <hip/hip_runtime.h>

typedef float f32x4 __attribute__((ext_vector_type(4)));

#define B_ 8
#define N_ 256
#define D_ 128

// ---------------------------------------------------------------------------
// Single fused kernel. 256 blocks x 512 threads.
// Block bid: batch b = bid&7 (XCD-affine under round-robin dispatch),
//            slot = bid>>3 -> 8 rows r0 = b*N + slot*8.
// Phase 1: 512 threads = 8 rows x 64 colgroups(f32x4) of the 256 concat cols.
//          A-half (+bias) -> LDS As;  C-half -> global C (1 MB in d_ws).
// Handshake: per-batch counter in d_ws (memset to 0 each call). Producers
//          release-add after their C stores; consumers acquire-spin for 32.
// Phase 2: thread = (fq 0..31, row-pair 0..3, jg 0..3 x 64 j). Each C load
//          feeds 2 rows x 3 packed ops. One LDS exchange over 4 j-groups.
// ---------------------------------------------------------------------------
__global__ __launch_bounds__(512, 4) void fused_relational_kernel(
    const float* __restrict__ x, const float* __restrict__ W,
    const float* __restrict__ bias, float* __restrict__ C,
    int* __restrict__ cnt, float* __restrict__ out) {

    __shared__ float xs[8][D_];     // 4 KB
    __shared__ f32x4 As[8][32];     // 4 KB  (A tile, bias folded)
    __shared__ f32x4 pr[4][8][32];  // 16 KB (phase-2 partials)

    const int bid  = blockIdx.x;        // 0..255
    const int b    = bid & 7;
    const int slot = bid >> 3;          // 0..31
    const int r0   = b * N_ + slot * 8; // flattened row index
    const int tid  = threadIdx.x;

    // stage x tile (8 rows x 128)
    if (tid < 256) {
        const int row = tid >> 5, dq = tid & 31;
        reinterpret_cast<f32x4*>(&xs[row][0])[dq] =
            *reinterpret_cast<const f32x4*>(x + (size_t)(r0 + row) * D_ + dq * 4);
    }
    __syncthreads();

    // ---- phase 1: GEMM (8 rows x 256 concat cols) ----
    {
        const int row = tid >> 6;       // 0..7
        const int cg  = tid & 63;       // concat colgroup
        const int isC = cg >> 5;
        const int cq  = cg & 31;        // f32x4 index within D
        const f32x4* __restrict__ Wv =
            reinterpret_cast<const f32x4*>(W + (isC ? D_ * D_ : 0)) + cq;
        f32x4 acc = {0.f, 0.f, 0.f, 0.f};
        #pragma unroll 8
        for (int d = 0; d < D_; ++d)
            acc += xs[row][d] * Wv[(size_t)d * 32];
        if (isC) {
            reinterpret_cast<f32x4*>(C)[(size_t)(r0 + row) * 32 + cq] = acc;
        } else {
            acc += reinterpret_cast<const f32x4*>(bias)[cq];
            As[row][cq] = acc;
        }
    }

    // ---- handshake: publish C, wait for this batch's 32 producers ----
    __syncthreads();   // drains this block's C stores (vmcnt(0) before barrier)
    if (tid == 0) {
        __threadfence();
        __hip_atomic_fetch_add(&cnt[b], 1, __ATOMIC_RELEASE,
                               __HIP_MEMORY_SCOPE_AGENT);
        while (__hip_atomic_load(&cnt[b], __ATOMIC_ACQUIRE,
                                 __HIP_MEMORY_SCOPE_AGENT) < 32)
            __builtin_amdgcn_s_sleep(2);
    }
    __syncthreads();

    // ---- phase 2: out[r0+i][f] = sum_j relu(As[i][f] + C[b,j,f]) ----
    {
        const int fq  = tid & 31;
        const int irp = (tid >> 5) & 3;   // row pair -> rows 2*irp, 2*irp+1
        const int jg  = tid >> 7;         // 0..3 -> 64 j each
        const f32x4 zero = {0.f, 0.f, 0.f, 0.f};
        const f32x4 av0 = As[irp * 2 + 0][fq];
        const f32x4 av1 = As[irp * 2 + 1][fq];
        const f32x4* __restrict__ Cb =
            reinterpret_cast<const f32x4*>(C) + (size_t)b * N_ * 32 + fq;
        f32x4 a0 = zero, a1 = zero;
        #pragma unroll 8
        for (int j = jg * 64; j < jg * 64 + 64; ++j) {
            const f32x4 cv = Cb[(size_t)j * 32];
            a0 += __builtin_elementwise_max(av0 + cv, zero);
            a1 += __builtin_elementwise_max(av1 + cv, zero);
        }
        pr[jg][irp * 2 + 0][fq] = a0;
        pr[jg][irp * 2 + 1][fq] = a1;
    }
    __syncthreads();
    if (tid < 256) {
        const int rr = tid >> 5, ff = tid & 31;
        const f32x4 s = pr[0][rr][ff] + pr[1][rr][ff] +
                        pr[2][rr][ff] + pr[3][rr][ff];
        reinterpret_cast<f32x4*>(out)[(size_t)(r0 + rr) * 32 + ff] = s;
    }
}

// Fallback (only if workspace too small): fully fused, recomputes C per row.
__global__ __launch_bounds__(128) void fused_naive_kernel(
    const float* __restrict__ x, const float* __restrict__ W,
    const float* __restrict__ bias, float* __restrict__ out) {
    const int r = blockIdx.x;
    const int b = r / N_;
    const int f = threadIdx.x;
    const float* __restrict__ xi = x + (size_t)r * D_;
    float a = bias[f];
    for (int d = 0; d < D_; ++d) a += xi[d] * W[d * D_ + f];
    float acc = 0.0f;
    const float* __restrict__ xb = x + (size_t)b * N_ * D_;
    for (int j = 0; j < N_; ++j) {
        const float* __restrict__ xj = xb + (size_t)j * D_;
        float c = 0.0f;
        for (int d = 0; d < D_; ++d) c += xj[d] * W[(D_ + d) * D_ + f];
        acc += fmaxf(a + c, 0.0f);
    }
    out[(size_t)r * D_ + f] = acc;
}

extern "C" void kernel_launch(void* const* d_in, const int* in_sizes, int n_in,
                              void* d_out, int out_size, void* d_ws, size_t ws_size,
                              hipStream_t stream) {
    const float* x    = (const float*)d_in[0];   // (B, N, D) fp32
    const float* W    = (const float*)d_in[1];   // (2D, D)   fp32
    const float* bias = (const float*)d_in[2];   // (D,)      fp32
    float* out = (float*)d_out;                  // (B, N, D) fp32

    const size_t c_bytes = (size_t)B_ * N_ * D_ * sizeof(float);  // 1 MB
    const size_t need    = c_bytes + 8 * sizeof(int);

    if (ws_size >= need) {
        float* C   = (float*)d_ws;
        int*   cnt = (int*)((char*)d_ws + c_bytes);
        hipMemsetAsync(cnt, 0, 8 * sizeof(int), stream);
        fused_relational_kernel<<<256, 512, 0, stream>>>(x, W, bias, C, cnt, out);
    } else {
        fused_naive_kernel<<<B_ * N_, D_, 0, stream>>>(x, W, bias, out);
    }
}

// Round 6
// 19.279 us; speedup vs baseline: 1.9471x; 1.9471x over previous
//
#include <hip/hip_runtime.h>

typedef float f32x4 __attribute__((ext_vector_type(4)));

#define B_ 8
#define N_ 256
#define D_ 128

// ---------------------------------------------------------------------------
// K1 (R2-proven): A[r][f] = sum_d x[r][d]*W[d][f] + bias[f];
//                 C[r][f] = sum_d x[r][d]*W[D+d][f]
// 256 blocks x 8 rows; 256 threads. W staged through LDS in 32-row chunks so
// every W element is fetched from L2 exactly once per block (32 MB chip-wide).
// Thread (rq,cq): rows {rq*2, rq*2+1}, cols cq*4..+3 of the 256 concat cols.
// ---------------------------------------------------------------------------
__global__ __launch_bounds__(256) void gemm_ac_kernel(
    const float* __restrict__ x, const float* __restrict__ W,
    const float* __restrict__ bias, float* __restrict__ A, float* __restrict__ C) {
    __shared__ float  xs[8][D_];    // 4 KB
    __shared__ float4 Ws[32][64];   // 32 KB: 32 d-rows x 256 concat cols

    const int tid  = threadIdx.x;
    const int r0   = blockIdx.x * 8;
    const int rq   = tid >> 6;      // 0..3
    const int cq   = tid & 63;      // 0..63 -> cols cq*4..+3
    const int halfC = cq >> 5;      // 0: A-half, 1: C-half
    const int f    = (cq * 4) & 127;

    // stage x tile (8 rows x 128)
    {
        const int row = tid >> 5;   // 0..7
        const int dq  = tid & 31;   // 0..31
        reinterpret_cast<float4*>(&xs[row][0])[dq] =
            *reinterpret_cast<const float4*>(x + (size_t)(r0 + row) * D_ + dq * 4);
    }

    float4 acc0 = make_float4(0.f, 0.f, 0.f, 0.f);
    float4 acc1 = make_float4(0.f, 0.f, 0.f, 0.f);

    for (int chunk = 0; chunk < 4; ++chunk) {
        if (chunk) __syncthreads();
        // cooperative W stage: 2048 float4 per chunk, 8 per thread
        #pragma unroll
        for (int k = 0; k < 8; ++k) {
            const int id = k * 256 + tid;
            const int dd = id >> 6;          // 0..31
            const int cg = id & 63;          // 0..63
            const int srow = chunk * 32 + dd + ((cg >> 5) << 7);  // +128 for C-half
            Ws[dd][cg] = *reinterpret_cast<const float4*>(
                W + (size_t)srow * D_ + (cg & 31) * 4);
        }
        __syncthreads();

        const int dbase = chunk * 32;
        #pragma unroll
        for (int dd = 0; dd < 32; ++dd) {
            const float4 wv = Ws[dd][cq];
            const float x0 = xs[rq * 2    ][dbase + dd];
            const float x1 = xs[rq * 2 + 1][dbase + dd];
            acc0.x += x0 * wv.x; acc0.y += x0 * wv.y;
            acc0.z += x0 * wv.z; acc0.w += x0 * wv.w;
            acc1.x += x1 * wv.x; acc1.y += x1 * wv.y;
            acc1.z += x1 * wv.z; acc1.w += x1 * wv.w;
        }
    }

    const int row0 = r0 + rq * 2;
    if (halfC) {
        *reinterpret_cast<float4*>(C + (size_t)row0 * D_ + f)       = acc0;
        *reinterpret_cast<float4*>(C + (size_t)(row0 + 1) * D_ + f) = acc1;
    } else {
        const float4 bv = *reinterpret_cast<const float4*>(bias + f);
        acc0.x += bv.x; acc0.y += bv.y; acc0.z += bv.z; acc0.w += bv.w;
        acc1.x += bv.x; acc1.y += bv.y; acc1.z += bv.z; acc1.w += bv.w;
        *reinterpret_cast<float4*>(A + (size_t)row0 * D_ + f)       = acc0;
        *reinterpret_cast<float4*>(A + (size_t)(row0 + 1) * D_ + f) = acc1;
    }
}

// ---------------------------------------------------------------------------
// K2 (R4-style): out[b,i,f] = sum_j relu(A'[b,i,f] + C[b,j,f]) (bias in A)
// grid 512 x block 256: block = (batch b, 4 rows i0..i0+3).
// tid = (jg 0..7) x (fq 0..31). Thread register-blocks 4 rows so each C
// float4 load feeds 4x3 packed ops; C panel read once per block
// (64 MB L2 chip-wide). One LDS exchange over the 8 j-groups at the end.
// ---------------------------------------------------------------------------
__global__ __launch_bounds__(256) void reduce_edges_kernel(
    const float* __restrict__ A, const float* __restrict__ C,
    float* __restrict__ out) {
    __shared__ f32x4 part[8][4][32];   // 16 KB

    const int blk = blockIdx.x;        // 0..511
    const int b   = blk >> 6;
    const int i0  = (blk & 63) * 4;
    const int tid = threadIdx.x;
    const int fq  = tid & 31;
    const int jg  = tid >> 5;          // 0..7

    f32x4 av[4], acc[4];
    const f32x4 zero = {0.f, 0.f, 0.f, 0.f};
    #pragma unroll
    for (int r = 0; r < 4; ++r) {
        av[r] = *reinterpret_cast<const f32x4*>(
            A + ((size_t)(b * N_ + i0 + r)) * D_ + fq * 4);
        acc[r] = zero;
    }

    const f32x4* __restrict__ Cv =
        reinterpret_cast<const f32x4*>(C + (size_t)b * N_ * D_) +
        (size_t)(jg * 32) * 32 + fq;
    #pragma unroll 4
    for (int j = 0; j < 32; ++j) {
        const f32x4 cv = Cv[(size_t)j * 32];
        #pragma unroll
        for (int r = 0; r < 4; ++r) {
            f32x4 t = av[r] + cv;                       // v_pk_add_f32
            t = __builtin_elementwise_max(t, zero);     // relu
            acc[r] += t;                                // v_pk_add_f32
        }
    }

    #pragma unroll
    for (int r = 0; r < 4; ++r) part[jg][r][fq] = acc[r];
    __syncthreads();

    if (tid < 128) {
        const int rr = tid >> 5, ff = tid & 31;
        f32x4 s = part[0][rr][ff];
        #pragma unroll
        for (int k = 1; k < 8; ++k) s += part[k][rr][ff];
        *reinterpret_cast<f32x4*>(
            out + ((size_t)(b * N_ + i0 + rr)) * D_ + ff * 4) = s;
    }
}

// Fallback (only if workspace too small): fully fused, recomputes C per row.
__global__ __launch_bounds__(128) void fused_naive_kernel(
    const float* __restrict__ x, const float* __restrict__ W,
    const float* __restrict__ bias, float* __restrict__ out) {
    const int r = blockIdx.x;
    const int b = r / N_;
    const int f = threadIdx.x;
    const float* __restrict__ xi = x + (size_t)r * D_;
    float a = bias[f];
    for (int d = 0; d < D_; ++d) a += xi[d] * W[d * D_ + f];
    float acc = 0.0f;
    const float* __restrict__ xb = x + (size_t)b * N_ * D_;
    for (int j = 0; j < N_; ++j) {
        const float* __restrict__ xj = xb + (size_t)j * D_;
        float c = 0.0f;
        for (int d = 0; d < D_; ++d) c += xj[d] * W[(D_ + d) * D_ + f];
        acc += fmaxf(a + c, 0.0f);
    }
    out[(size_t)r * D_ + f] = acc;
}

extern "C" void kernel_launch(void* const* d_in, const int* in_sizes, int n_in,
                              void* d_out, int out_size, void* d_ws, size_t ws_size,
                              hipStream_t stream) {
    const float* x    = (const float*)d_in[0];   // (B, N, D) fp32
    const float* W    = (const float*)d_in[1];   // (2D, D)   fp32
    const float* bias = (const float*)d_in[2];   // (D,)      fp32
    float* out = (float*)d_out;                  // (B, N, D) fp32

    const size_t elems = (size_t)B_ * N_ * D_;
    const size_t need  = 2 * elems * sizeof(float);

    if (ws_size >= need) {
        float* A = (float*)d_ws;
        float* C = A + elems;
        gemm_ac_kernel<<<(B_ * N_) / 8, 256, 0, stream>>>(x, W, bias, A, C);
        reduce_edges_kernel<<<(B_ * N_) / 4, 256, 0, stream>>>(A, C, out);
    } else {
        fused_naive_kernel<<<B_ * N_, D_, 0, stream>>>(x, W, bias, out);
    }
}